// Round 1
// baseline (66.310 us; speedup 1.0000x reference)
//
#include <hip/hip_runtime.h>

// Problem constants (from setup_inputs): palettes [16,64,3] f32, images [16,3,256,256] f32.
constexpr int Bsz = 16;
constexpr int Kp  = 64;
constexpr int HW  = 256 * 256;          // 65536 pixels per image
constexpr int BPB = 64;                 // blocks per batch image
constexpr int NBLK = Bsz * BPB;         // 1024 blocks; 256 thr x 4 px = 1024 px/block
constexpr float ALPHA = 0.001f;

// Kernel 1: per-pixel nearest-palette squared distance, summed per block.
// mse contribution of a pixel == min_k ||pixel - palette_k||^2 (no index needed).
__global__ __launch_bounds__(256) void quant_mse_kernel(
    const float* __restrict__ palettes,
    const float* __restrict__ images,
    float* __restrict__ partials)
{
    __shared__ float pr[Kp], pg[Kp], pb[Kp];
    const int b   = blockIdx.x >> 6;        // BPB = 64
    const int blk = blockIdx.x & (BPB - 1);
    const int t   = threadIdx.x;

    if (t < Kp) {
        const float* p = palettes + (size_t)(b * Kp + t) * 3;
        pr[t] = p[0]; pg[t] = p[1]; pb[t] = p[2];
    }
    __syncthreads();

    const float* img  = images + (size_t)b * 3 * HW;  // planar: R plane, G plane, B plane
    const int    base = blk * 1024 + t * 4;           // 4 consecutive pixels per thread

    const float4 rv = *(const float4*)(img + base);
    const float4 gv = *(const float4*)(img + HW + base);
    const float4 bv = *(const float4*)(img + 2 * HW + base);
    float rr[4] = {rv.x, rv.y, rv.z, rv.w};
    float gg[4] = {gv.x, gv.y, gv.z, gv.w};
    float bb[4] = {bv.x, bv.y, bv.z, bv.w};
    float best[4] = {1e30f, 1e30f, 1e30f, 1e30f};

    #pragma unroll 16
    for (int k = 0; k < Kp; ++k) {
        const float cr = pr[k], cg = pg[k], cb = pb[k];  // LDS broadcast (conflict-free)
        #pragma unroll
        for (int i = 0; i < 4; ++i) {
            const float dr = rr[i] - cr;
            const float dg = gg[i] - cg;
            const float db = bb[i] - cb;
            const float d2 = fmaf(db, db, fmaf(dg, dg, dr * dr));
            best[i] = fminf(best[i], d2);
        }
    }

    float acc = (best[0] + best[1]) + (best[2] + best[3]);

    // wave64 shuffle reduce
    #pragma unroll
    for (int off = 32; off > 0; off >>= 1)
        acc += __shfl_down(acc, off, 64);

    __shared__ float wsum[4];
    const int lane = t & 63, wid = t >> 6;
    if (lane == 0) wsum[wid] = acc;
    __syncthreads();
    if (t == 0)
        partials[blockIdx.x] = (wsum[0] + wsum[1]) + (wsum[2] + wsum[3]);
}

// Kernel 2 (1 block): palette pairwise term + reduce partials + combine.
__global__ __launch_bounds__(256) void finalize_kernel(
    const float* __restrict__ palettes,
    const float* __restrict__ partials,
    float* __restrict__ out)
{
    const int t = threadIdx.x;

    // Pairwise palette distances, upper triangle i<j. Iterate all B*K*K cells,
    // skip i>=j (half the lanes idle; total work is tiny: 64k cells).
    float pacc = 0.f;
    for (int idx = t; idx < Bsz * Kp * Kp; idx += 256) {
        const int b   = idx >> 12;          // Kp*Kp = 4096
        const int rem = idx & 4095;
        const int i   = rem >> 6;
        const int j   = rem & 63;
        if (i < j) {
            const float* pi = palettes + (size_t)(b * Kp + i) * 3;
            const float* pj = palettes + (size_t)(b * Kp + j) * 3;
            const float dr = pi[0] - pj[0];
            const float dg = pi[1] - pj[1];
            const float db = pi[2] - pj[2];
            pacc += sqrtf(fmaf(db, db, fmaf(dg, dg, dr * dr)));
        }
    }

    // Sum the per-block mse partials (1024 of them).
    float macc = 0.f;
    for (int i = t; i < NBLK; i += 256) macc += partials[i];

    #pragma unroll
    for (int off = 32; off > 0; off >>= 1) {
        pacc += __shfl_down(pacc, off, 64);
        macc += __shfl_down(macc, off, 64);
    }
    __shared__ float pw[4], mw[4];
    const int lane = t & 63, wid = t >> 6;
    if (lane == 0) { pw[wid] = pacc; mw[wid] = macc; }
    __syncthreads();
    if (t == 0) {
        const float ps = (pw[0] + pw[1]) + (pw[2] + pw[3]);
        const float ms = (mw[0] + mw[1]) + (mw[2] + mw[3]);
        const float mse = ms / (float)((size_t)Bsz * 3 * HW);           // mean over 3,145,728
        const float pl  = ps / (float)(Bsz * (Kp * (Kp - 1) / 2));      // / (2016 * 16)
        out[0] = mse - ALPHA * pl;
    }
}

extern "C" void kernel_launch(void* const* d_in, const int* in_sizes, int n_in,
                              void* d_out, int out_size, void* d_ws, size_t ws_size,
                              hipStream_t stream) {
    const float* palettes = (const float*)d_in[0];   // [16,64,3]
    const float* images   = (const float*)d_in[1];   // [16,3,256,256]
    float* out      = (float*)d_out;
    float* partials = (float*)d_ws;                  // NBLK floats

    quant_mse_kernel<<<NBLK, 256, 0, stream>>>(palettes, images, partials);
    finalize_kernel<<<1, 256, 0, stream>>>(palettes, partials, out);
}

// Round 2
// 24.321 us; speedup vs baseline: 2.7264x; 2.7264x over previous
//
#include <hip/hip_runtime.h>

// Problem constants (from setup_inputs): palettes [16,64,3] f32, images [16,3,256,256] f32.
constexpr int Bsz = 16;
constexpr int Kp  = 64;
constexpr int HW  = 256 * 256;          // 65536 pixels per image
constexpr int BPB = 64;                 // blocks per batch image
constexpr int NBLK = Bsz * BPB;         // 1024 blocks; 256 thr x 4 px = 1024 px/block
constexpr float ALPHA = 0.001f;

// Kernel 1: per-pixel nearest-palette squared distance, summed per block.
// min_k ||x-p||^2 = ||x||^2 + min_k(||p||^2 - 2 x.p)  -> 3 fma + 1 min per (pixel,k).
__global__ __launch_bounds__(256) void quant_mse_kernel(
    const float* __restrict__ palettes,
    const float* __restrict__ images,
    float* __restrict__ partials)
{
    __shared__ float m2r[Kp], m2g[Kp], m2b[Kp], c2[Kp];
    const int b   = blockIdx.x >> 6;        // BPB = 64
    const int blk = blockIdx.x & (BPB - 1);
    const int t   = threadIdx.x;

    if (t < Kp) {
        const float* p = palettes + (size_t)(b * Kp + t) * 3;
        const float r = p[0], g = p[1], bl = p[2];
        m2r[t] = -2.f * r; m2g[t] = -2.f * g; m2b[t] = -2.f * bl;
        c2[t]  = fmaf(r, r, fmaf(g, g, bl * bl));
    }
    __syncthreads();

    const float* img  = images + (size_t)b * 3 * HW;  // planar R,G,B planes
    const int    base = blk * 1024 + t * 4;           // 4 consecutive pixels per thread

    const float4 rv = *(const float4*)(img + base);
    const float4 gv = *(const float4*)(img + HW + base);
    const float4 bv = *(const float4*)(img + 2 * HW + base);
    float rr[4] = {rv.x, rv.y, rv.z, rv.w};
    float gg[4] = {gv.x, gv.y, gv.z, gv.w};
    float bb[4] = {bv.x, bv.y, bv.z, bv.w};
    float best[4] = {1e30f, 1e30f, 1e30f, 1e30f};

    #pragma unroll 16
    for (int k = 0; k < Kp; ++k) {
        const float kr = m2r[k], kg = m2g[k], kb = m2b[k], kc = c2[k]; // LDS broadcast
        #pragma unroll
        for (int i = 0; i < 4; ++i) {
            float d = fmaf(rr[i], kr, kc);
            d = fmaf(gg[i], kg, d);
            d = fmaf(bb[i], kb, d);
            best[i] = fminf(best[i], d);
        }
    }

    float acc = 0.f;
    #pragma unroll
    for (int i = 0; i < 4; ++i) {
        const float x2 = fmaf(rr[i], rr[i], fmaf(gg[i], gg[i], bb[i] * bb[i]));
        acc += best[i] + x2;
    }

    // wave64 shuffle reduce
    #pragma unroll
    for (int off = 32; off > 0; off >>= 1)
        acc += __shfl_down(acc, off, 64);

    __shared__ float wsum[4];
    const int lane = t & 63, wid = t >> 6;
    if (lane == 0) wsum[wid] = acc;
    __syncthreads();
    if (t == 0)
        partials[blockIdx.x] = (wsum[0] + wsum[1]) + (wsum[2] + wsum[3]);
}

// Kernel 2 (1 block x 1024 threads): palette pairwise term from LDS +
// reduce mse partials + combine. LDS-staged palettes kill the global-load
// latency chain that dominated the previous version.
__global__ __launch_bounds__(1024) void finalize_kernel(
    const float* __restrict__ palettes,
    const float* __restrict__ partials,
    float* __restrict__ out)
{
    __shared__ float pal[Bsz * Kp * 3];   // 12 KB
    const int t = threadIdx.x;

    for (int i = t; i < Bsz * Kp * 3; i += 1024)
        pal[i] = palettes[i];
    __syncthreads();

    // Pairwise distances over all B*K*K cells, mask i<j. Two accumulators
    // to break the dependent-add chain (64 iters -> 2x32).
    float pacc0 = 0.f, pacc1 = 0.f;
    #pragma unroll 4
    for (int idx = t; idx < Bsz * Kp * Kp; idx += 2048) {
        {
            const int b = idx >> 12, rem = idx & 4095;
            const int i = rem >> 6, j = rem & 63;
            if (i < j) {
                const float* pi = pal + (b * Kp + i) * 3;   // broadcast within wave
                const float* pj = pal + (b * Kp + j) * 3;   // stride-3: conflict-free
                const float dr = pi[0] - pj[0];
                const float dg = pi[1] - pj[1];
                const float db = pi[2] - pj[2];
                pacc0 += sqrtf(fmaf(db, db, fmaf(dg, dg, dr * dr)));
            }
        }
        {
            const int idx1 = idx + 1024;
            const int b = idx1 >> 12, rem = idx1 & 4095;
            const int i = rem >> 6, j = rem & 63;
            if (i < j) {
                const float* pi = pal + (b * Kp + i) * 3;
                const float* pj = pal + (b * Kp + j) * 3;
                const float dr = pi[0] - pj[0];
                const float dg = pi[1] - pj[1];
                const float db = pi[2] - pj[2];
                pacc1 += sqrtf(fmaf(db, db, fmaf(dg, dg, dr * dr)));
            }
        }
    }
    float pacc = pacc0 + pacc1;

    // Each of the 1024 threads owns exactly one mse partial.
    float macc = partials[t];

    #pragma unroll
    for (int off = 32; off > 0; off >>= 1) {
        pacc += __shfl_down(pacc, off, 64);
        macc += __shfl_down(macc, off, 64);
    }
    __shared__ float pw[16], mw[16];
    const int lane = t & 63, wid = t >> 6;
    if (lane == 0) { pw[wid] = pacc; mw[wid] = macc; }
    __syncthreads();
    if (t == 0) {
        float ps = 0.f, ms = 0.f;
        #pragma unroll
        for (int w = 0; w < 16; ++w) { ps += pw[w]; ms += mw[w]; }
        const float mse = ms / (float)((size_t)Bsz * 3 * HW);        // / 3,145,728
        const float pl  = ps / (float)(Bsz * (Kp * (Kp - 1) / 2));   // / (2016 * 16)
        out[0] = mse - ALPHA * pl;
    }
}

extern "C" void kernel_launch(void* const* d_in, const int* in_sizes, int n_in,
                              void* d_out, int out_size, void* d_ws, size_t ws_size,
                              hipStream_t stream) {
    const float* palettes = (const float*)d_in[0];   // [16,64,3]
    const float* images   = (const float*)d_in[1];   // [16,3,256,256]
    float* out      = (float*)d_out;
    float* partials = (float*)d_ws;                  // NBLK floats

    quant_mse_kernel<<<NBLK, 256, 0, stream>>>(palettes, images, partials);
    finalize_kernel<<<1, 1024, 0, stream>>>(palettes, partials, out);
}

// Round 3
// 15.822 us; speedup vs baseline: 4.1911x; 1.5372x over previous
//
#include <hip/hip_runtime.h>

// Problem constants (from setup_inputs): palettes [16,64,3] f32, images [16,3,256,256] f32.
constexpr int Bsz = 16;
constexpr int Kp  = 64;
constexpr int HW  = 256 * 256;          // 65536 pixels per image
constexpr int BPB = 64;                 // blocks per batch image
constexpr int NBLK = Bsz * BPB;         // 1024 blocks; 256 thr x 4 px = 1024 px/block
constexpr float ALPHA = 0.001f;
constexpr float NPIX  = 3145728.0f;     // 16*3*256*256 (mse mean denominator)
constexpr float NCOMB = 32256.0f;       // K*(K-1)/2 * B = 2016*16
// Pairwise contribution is pre-scaled so that (sum of partials)/NPIX == final loss.
constexpr float PAIR_SCALE = -ALPHA * (NPIX / NCOMB);   // -0.0975238...

// Kernel 1: per-pixel nearest-palette squared distance, summed per block.
// min_k ||x-p||^2 = ||x||^2 + min_k(||p||^2 - 2 x.p)  -> 3 fma per (pixel,k) + min3 per pair.
// Additionally, the blk==0 block of each batch folds in that batch's pairwise
// palette term (pre-scaled by PAIR_SCALE).
__global__ __launch_bounds__(256) void quant_mse_kernel(
    const float* __restrict__ palettes,
    const float* __restrict__ images,
    float* __restrict__ partials)
{
    __shared__ float4 kc4[Kp];                 // (-2r, -2g, -2b, r^2+g^2+b^2)
    __shared__ float  pr[Kp], pg[Kp], pb[Kp];  // raw palette (for pairwise term)
    const int b   = blockIdx.x >> 6;        // BPB = 64
    const int blk = blockIdx.x & (BPB - 1);
    const int t   = threadIdx.x;

    if (t < Kp) {
        const float* p = palettes + (size_t)(b * Kp + t) * 3;
        const float r = p[0], g = p[1], bl = p[2];
        pr[t] = r; pg[t] = g; pb[t] = bl;
        kc4[t] = make_float4(-2.f * r, -2.f * g, -2.f * bl,
                             fmaf(r, r, fmaf(g, g, bl * bl)));
    }
    __syncthreads();

    const float* img  = images + (size_t)b * 3 * HW;  // planar R,G,B planes
    const int    base = blk * 1024 + t * 4;           // 4 consecutive pixels per thread

    const float4 rv = *(const float4*)(img + base);
    const float4 gv = *(const float4*)(img + HW + base);
    const float4 bv = *(const float4*)(img + 2 * HW + base);
    float rr[4] = {rv.x, rv.y, rv.z, rv.w};
    float gg[4] = {gv.x, gv.y, gv.z, gv.w};
    float bb[4] = {bv.x, bv.y, bv.z, bv.w};
    float best[4] = {1e30f, 1e30f, 1e30f, 1e30f};

    #pragma unroll 8
    for (int k = 0; k < Kp; k += 2) {
        const float4 c0 = kc4[k];       // one ds_read_b128, wave-broadcast
        const float4 c1 = kc4[k + 1];
        #pragma unroll
        for (int i = 0; i < 4; ++i) {
            float d0 = fmaf(rr[i], c0.x, c0.w);
            d0 = fmaf(gg[i], c0.y, d0);
            d0 = fmaf(bb[i], c0.z, d0);
            float d1 = fmaf(rr[i], c1.x, c1.w);
            d1 = fmaf(gg[i], c1.y, d1);
            d1 = fmaf(bb[i], c1.z, d1);
            best[i] = fminf(best[i], fminf(d0, d1));   // -> v_min3_f32
        }
    }

    float acc = 0.f;
    #pragma unroll
    for (int i = 0; i < 4; ++i) {
        const float x2 = fmaf(rr[i], rr[i], fmaf(gg[i], gg[i], bb[i] * bb[i]));
        acc += best[i] + x2;
    }

    // One block per batch folds in the (pre-scaled) pairwise palette term.
    if (blk == 0) {
        float pacc = 0.f;
        #pragma unroll
        for (int m = 0; m < Kp * Kp / 256; ++m) {      // 16 cells per thread
            const int idx = t + m * 256;
            const int i = idx >> 6, j = idx & 63;      // i wave-uniform, j = lane
            if (i < j) {
                const float dr = pr[i] - pr[j];
                const float dg = pg[i] - pg[j];
                const float db = pb[i] - pb[j];
                pacc += sqrtf(fmaf(db, db, fmaf(dg, dg, dr * dr)));
            }
        }
        acc = fmaf(PAIR_SCALE, pacc, acc);
    }

    // wave64 shuffle reduce
    #pragma unroll
    for (int off = 32; off > 0; off >>= 1)
        acc += __shfl_down(acc, off, 64);

    __shared__ float wsum[4];
    const int lane = t & 63, wid = t >> 6;
    if (lane == 0) wsum[wid] = acc;
    __syncthreads();
    if (t == 0)
        partials[blockIdx.x] = (wsum[0] + wsum[1]) + (wsum[2] + wsum[3]);
}

// Kernel 2 (1 block x 1024 threads): pure sum of the 1024 partials.
__global__ __launch_bounds__(1024) void finalize_kernel(
    const float* __restrict__ partials,
    float* __restrict__ out)
{
    const int t = threadIdx.x;
    float acc = partials[t];

    #pragma unroll
    for (int off = 32; off > 0; off >>= 1)
        acc += __shfl_down(acc, off, 64);

    __shared__ float wsum[16];
    const int lane = t & 63, wid = t >> 6;
    if (lane == 0) wsum[wid] = acc;
    __syncthreads();
    if (t == 0) {
        float s = 0.f;
        #pragma unroll
        for (int w = 0; w < 16; ++w) s += wsum[w];
        out[0] = s / NPIX;
    }
}

extern "C" void kernel_launch(void* const* d_in, const int* in_sizes, int n_in,
                              void* d_out, int out_size, void* d_ws, size_t ws_size,
                              hipStream_t stream) {
    const float* palettes = (const float*)d_in[0];   // [16,64,3]
    const float* images   = (const float*)d_in[1];   // [16,3,256,256]
    float* out      = (float*)d_out;
    float* partials = (float*)d_ws;                  // NBLK floats

    quant_mse_kernel<<<NBLK, 256, 0, stream>>>(palettes, images, partials);
    finalize_kernel<<<1, 1024, 0, stream>>>(partials, out);
}